// Round 12
// baseline (436.599 us; speedup 1.0000x reference)
//
#include <hip/hip_runtime.h>
#include <stdint.h>

#pragma clang fp contract(off)

#define STEPS 50
#define BSZ 32
#define NN 64
#define DXC 8
#define DEC 5
// Output order (scan-unpack): out0=stacked Xn, out1=stacked En,
// out2=stacked Xc, out3=stacked Ec.
#define OFF_TOTE 819200UL     // out1 base (elements)
#define OFF_OUTX 33587200UL   // out2 base
#define OFF_OUTE 34406400UL   // out3 base

#define NPAIR 2016            // upper-tri pairs per batch
#define EDGE_CHAINS 64512     // 32*2016
#define EDGE_BLOCKS 1344      // 64512 chains / (12 groups * 4 waves)
// ws layout (bytes)
#define WS_KEYS 0UL            // u32[256]: kx[0..99], ke[100..199], cnt[200]
#define WS_STE  1024UL         // f32[1250]  edge log-prob table
#define WS_STN  6144UL         // f32[3200]  node log-prob table
#define WS_CL   18944UL        // u16[64512] compacted chain ids
#define WS_CB   147968UL       // u32[64512] chain counter-base (=crow)
#define WS_S2E  406016UL       // u8[1600][2016] samples, slab-major
#define WS_S2N  3631616UL      // u8[1600][64]
#define WS_NEED 3734016UL

// ---------------- threefry2x32 (JAX-exact, 20 rounds) ----------------
__device__ __forceinline__ uint32_t rotl32(uint32_t x, int d) {
  return (x << d) | (x >> (32 - d));
}

__device__ __forceinline__ void tf2x32(uint32_t k0, uint32_t k1,
                                       uint32_t x0, uint32_t x1,
                                       uint32_t& o0, uint32_t& o1) {
  uint32_t ks2 = k0 ^ k1 ^ 0x1BD11BDAu;
  x0 += k0; x1 += k1;
#define TF_R(r) { x0 += x1; x1 = rotl32(x1, (r)); x1 ^= x0; }
  TF_R(13) TF_R(15) TF_R(26) TF_R(6)
  x0 += k1; x1 += ks2 + 1u;
  TF_R(17) TF_R(29) TF_R(16) TF_R(24)
  x0 += ks2; x1 += k0 + 2u;
  TF_R(13) TF_R(15) TF_R(26) TF_R(6)
  x0 += k0; x1 += k1 + 3u;
  TF_R(17) TF_R(29) TF_R(16) TF_R(24)
  x0 += k1; x1 += ks2 + 4u;
  TF_R(13) TF_R(15) TF_R(26) TF_R(6)
  x0 += ks2; x1 += k0 + 5u;
#undef TF_R
  o0 = x0; o1 = x1;
}

__device__ __forceinline__ float logf_cr(float x) { return (float)log((double)x); }
__device__ __forceinline__ float expf_cr(float x) { return (float)exp((double)x); }

// JAX PARTITIONABLE random_bits: bits[i] = o0 ^ o1 of cipher(key, (hi=0, lo=i));
// uniform(tiny,1) == max(uf, tiny) bit-exactly; gumbel = -log(-log(u)) fp32 CR.
__device__ __forceinline__ float gumbel_inl(uint32_t k0, uint32_t k1,
                                            uint32_t idx) {
  uint32_t o0, o1;
  tf2x32(k0, k1, 0u, idx, o0, o1);
  uint32_t bits = o0 ^ o1;
  float uf = __uint_as_float((bits >> 9) | 0x3f800000u) - 1.0f;
  float u = fmaxf(uf, 1.1754943508222875e-38f);
  return -logf_cr(-logf_cr(u));
}
__device__ __attribute__((noinline)) float gumbel_part(uint32_t k0, uint32_t k1,
                                                       uint32_t idx) {
  return gumbel_inl(k0, k1, idx);
}

// dtype auto-detect on X's first 32 bytes.
__device__ __forceinline__ bool detect_bf16(const void* X) {
  const uint16_t* u = (const uint16_t*)X;
  int c = 0;
  for (int i = 0; i < 16; ++i) c += (u[i] == 0x3F80u);
  return c >= 2;
}

__device__ __forceinline__ float ld(const void* p, size_t i, bool bf) {
  if (bf) return __uint_as_float(((uint32_t)((const uint16_t*)p)[i]) << 16);
  return ((const float*)p)[i];
}
__device__ __forceinline__ void st(void* p, size_t i, bool bf, float v) {
  if (bf) ((uint16_t*)p)[i] = (uint16_t)(__float_as_uint(v) >> 16);
  else ((float*)p)[i] = v;
}
__device__ __forceinline__ void stv4(void* p, size_t e4, bool bf,
                                     float a, float b, float c, float d) {
  if (!bf) {
    float4 v; v.x = a; v.y = b; v.z = c; v.w = d;
    ((float4*)p)[e4] = v;
  } else {
    ushort4 v;
    v.x = (uint16_t)(__float_as_uint(a) >> 16);
    v.y = (uint16_t)(__float_as_uint(b) >> 16);
    v.z = (uint16_t)(__float_as_uint(c) >> 16);
    v.w = (uint16_t)(__float_as_uint(d) >> 16);
    ((ushort4*)p)[e4] = v;
  }
}
__device__ __forceinline__ void cpy4(void* dst, const void* src, size_t de4,
                                     size_t se4, bool bf) {
  if (!bf) ((float4*)dst)[de4] = ((const float4*)src)[se4];
  else ((uint2*)dst)[de4] = ((const uint2*)src)[se4];
}

__device__ __forceinline__ bool read_mask(const void* mp, int idx) {
  const uint8_t* m8 = (const uint8_t*)mp;
  uint8_t b1 = m8[1];
  if (b1 == 0) return ((const uint32_t*)mp)[idx] != 0;
  if (b1 == 0x3F) return ((const uint16_t*)mp)[idx] != 0;
  return m8[idx] != 0;
}

// fp32 pred pipeline for current class c, reference op order, exp/log CR.
template <int D>
__device__ void fill_logp(const void* __restrict__ W, bool bf, float gamma,
                          int c, float* __restrict__ out) {
  float t[D];
  for (int d = 0; d < D; ++d) t[d] = ld(W, c * D + d, bf);
  float m = t[0];
  for (int d = 1; d < D; ++d) m = fmaxf(m, t[d]);
  float u[D];
  for (int d = 0; d < D; ++d) u[d] = expf_cr(t[d] - m);
  float s = 0.0f;
  for (int d = 0; d < D; ++d) s += u[d];
  float p[D];
  for (int d = 0; d < D; ++d) p[d] = (u[d] / s) * gamma;
  p[c] = 0.0f;
  float s1 = 0.0f;
  for (int d = 0; d < D; ++d) s1 += p[d];
  float r = fmaxf(1.0f - s1, 0.0f);
  p[c] = r;
  float s2 = 0.0f;
  for (int d = 0; d < D; ++d) s2 += p[d];
  for (int d = 0; d < D; ++d) out[d] = logf_cr(p[d] / s2);
}

__device__ __forceinline__ void pair_decode(int q, int& lo, int& hi) {
  lo = 0; int rem = q;
  while (rem >= 63 - lo) { rem -= 63 - lo; lo++; }
  hi = lo + 1 + rem;
}

// ---------------- K0: keys + both log-prob tables + zero counter -----------
__global__ __launch_bounds__(256) void prep_kernel(
    const void* __restrict__ X, const void* __restrict__ gammas,
    const void* __restrict__ Wx, const void* __restrict__ We,
    uint8_t* __restrict__ ws) {
  const int t = threadIdx.x;
  const bool bf = detect_bf16(X);
  uint32_t* wk = (uint32_t*)(ws + WS_KEYS);
  if (t == 0) wk[200] = 0u;
  if (t < STEPS) {
    uint32_t f0, f1, a0, a1;
    tf2x32(0u, 42u, 0u, (uint32_t)t, f0, f1);
    tf2x32(f0, f1, 0u, 0u, a0, a1);  // kx
    wk[2 * t] = a0; wk[2 * t + 1] = a1;
    tf2x32(f0, f1, 0u, 1u, a0, a1);  // ke
    wk[100 + 2 * t] = a0; wk[101 + 2 * t] = a1;
  }
  for (int task = t; task < STEPS * DEC; task += 256)
    fill_logp<DEC>(We, bf, ld(gammas, task / DEC, bf), task % DEC,
                   (float*)(ws + WS_STE) + task * DEC);
  for (int task = t; task < STEPS * DXC; task += 256)
    fill_logp<DXC>(Wx, bf, ld(gammas, task / DXC, bf), task % DXC,
                   (float*)(ws + WS_STN) + task * DXC);
}

// ---------------- Kc: compact valid edge chains -> ids + counter bases -----
__global__ __launch_bounds__(256) void compact_kernel(const void* __restrict__ M,
                                                      uint8_t* __restrict__ ws) {
  int chain = blockIdx.x * 256 + threadIdx.x;
  if (chain >= EDGE_CHAINS) return;
  int b = chain / NPAIR, q = chain % NPAIR, lo, hi;
  pair_decode(q, lo, hi);
  if (read_mask(M, b * NN + lo) && read_mask(M, b * NN + hi)) {
    uint32_t slot = atomicAdd((uint32_t*)(ws + WS_KEYS) + 200, 1u);
    ((uint16_t*)(ws + WS_CL))[slot] = (uint16_t)chain;
    ((uint32_t*)(ws + WS_CB))[slot] =
        (uint32_t)(((b * NN + lo) * NN + hi) * DEC);
  }
}

// ---------------- K1: fused gumbel+argmax chains, lane-group parallel ------
// blocks [0,1344): edge — 5 lanes per compacted chain, 12 groups/wave.
// blocks [1344,1408): node — 8 lanes per node chain, 8 groups/wave.
__global__ __launch_bounds__(256) void chain_kernel(
    const void* __restrict__ X, const void* __restrict__ E,
    const void* __restrict__ M, uint8_t* __restrict__ ws) {
  __shared__ float stab[STEPS * DXC * DXC];
  __shared__ uint32_t skeys[STEPS * 2];
  const bool edge_blk = blockIdx.x < EDGE_BLOCKS;
  const int t = threadIdx.x;
  const bool bf = detect_bf16(X);
  const uint32_t* wk = (const uint32_t*)(ws + WS_KEYS);

  // stage table + step keys
  if (edge_blk) {
    for (int x = t; x < STEPS * DEC * DEC; x += 256)
      stab[x] = ((const float*)(ws + WS_STE))[x];
    if (t < STEPS * 2) skeys[t] = wk[100 + t];
  } else {
    for (int x = t; x < STEPS * DXC * DXC; x += 256)
      stab[x] = ((const float*)(ws + WS_STN))[x];
    if (t < STEPS * 2) skeys[t] = wk[t];
  }
  __syncthreads();

  const int lane = t & 63;
  if (edge_blk) {
    if (lane >= 60) return;  // 12 groups of 5 per wave
    const uint32_t cnt = wk[200];
    int grp = lane / 5, d = lane - grp * 5, gb = (t & ~63) % 64 + grp * 5;
    // group base lane within wave for shfl: lanes are wave-relative
    gb = grp * 5;
    uint32_t slot = (uint32_t)((blockIdx.x * 4 + (t >> 6)) * 12 + grp);
    if (slot >= cnt) return;
    int chain = (int)((const uint16_t*)(ws + WS_CL))[slot];
    uint32_t cb = ((const uint32_t*)(ws + WS_CB))[slot];
    int b = chain / NPAIR, q = chain - b * NPAIR;
    // init: first-max argmax of E row (sequential order via shfl gather)
    float v = ld(E, (size_t)cb + d, bf);
    int cur = 0;
    {
      float bst = __shfl(v, gb, 64);
      for (int j = 1; j < DEC; ++j) {
        float vj = __shfl(v, gb + j, 64);
        if (vj > bst) { bst = vj; cur = j; }
      }
    }
    uint8_t* s2e = ws + WS_S2E;
#pragma clang loop unroll(disable)
    for (int k = 0; k < STEPS; ++k) {
      float g = gumbel_part(skeys[2 * k], skeys[2 * k + 1], cb + (uint32_t)d);
      float s = stab[(k * DEC + cur) * DEC + d] + g;  // fp32 add
      int nxt = 0;
      {
        float bst = __shfl(s, gb, 64);
        for (int j = 1; j < DEC; ++j) {
          float sj = __shfl(s, gb + j, 64);
          if (sj > bst) { bst = sj; nxt = j; }  // first-max, like jnp.argmax
        }
      }
      if (d == 0) s2e[(size_t)(b * STEPS + k) * NPAIR + q] = (uint8_t)nxt;
      cur = nxt;
    }
  } else {
    int grp = lane >> 3, d = lane & 7, gb = grp * 8;
    int node = ((int)blockIdx.x - EDGE_BLOCKS) * 32 + (t >> 3);
    if (node >= BSZ * NN) return;
    if (!read_mask(M, node)) return;
    int b = node >> 6, i = node & 63;
    float v = ld(X, (size_t)node * DXC + d, bf);
    int cur = 0;
    {
      float bst = __shfl(v, gb, 64);
      for (int j = 1; j < DXC; ++j) {
        float vj = __shfl(v, gb + j, 64);
        if (vj > bst) { bst = vj; cur = j; }
      }
    }
    uint8_t* s2n = ws + WS_S2N;
#pragma clang loop unroll(disable)
    for (int k = 0; k < STEPS; ++k) {
      float g = gumbel_part(skeys[2 * k], skeys[2 * k + 1],
                            (uint32_t)(node * DXC + d));
      float s = stab[(k * DXC + cur) * DXC + d] + g;
      int nxt = 0;
      {
        float bst = __shfl(s, gb, 64);
        for (int j = 1; j < DXC; ++j) {
          float sj = __shfl(s, gb + j, 64);
          if (sj > bst) { bst = sj; nxt = j; }
        }
      }
      if (d == 0) s2n[(size_t)(b * STEPS + k) * 64 + i] = (uint8_t)nxt;
      cur = nxt;
    }
  }
}

// ---------------- K3: slab writer, float4 stores ----------------
// blocks [0,1600): edge slab (b,k); [1600,1632): node batch b (all k).
__global__ __launch_bounds__(256) void write_kernel(
    const void* __restrict__ X, const void* __restrict__ E,
    const void* __restrict__ M, const uint8_t* __restrict__ ws,
    void* __restrict__ out) {
  __shared__ uint8_t cur_g[4096];
  __shared__ uint8_t pre_g[4096];
  __shared__ uint8_t sc[NPAIR];
  __shared__ uint8_t sp_[NPAIR];
  __shared__ uint8_t sn[3200];
  __shared__ uint8_t vf[64];
  const bool bf = detect_bf16(X);
  const int t = threadIdx.x;

  if (blockIdx.x < 1600) {
    int slab = blockIdx.x;  // b*50+k
    int b = slab / STEPS, k = slab % STEPS;
    if (t < 64) vf[t] = read_mask(M, b * NN + t) ? 1 : 0;
    const uint8_t* s2e = ws + WS_S2E;
    for (int x = t; x < 504; x += 256) {
      ((uint32_t*)sc)[x] = ((const uint32_t*)(s2e + (size_t)slab * NPAIR))[x];
      if (k > 0)
        ((uint32_t*)sp_)[x] =
            ((const uint32_t*)(s2e + (size_t)(slab - 1) * NPAIR))[x];
    }
    __syncthreads();
    for (int ij = t; ij < 4096; ij += 256) {
      int i = ij >> 6, j = ij & 63;
      uint8_t c = 0xFF, p = 0xFF;
      if (i != j && vf[i] && vf[j]) {
        int lo = i < j ? i : j, hi = i < j ? j : i;
        int q = 63 * lo - ((lo * (lo - 1)) >> 1) + hi - lo - 1;
        c = sc[q];
        if (k > 0) p = sp_[q];
      }
      cur_g[ij] = c; pre_g[ij] = p;
    }
    __syncthreads();
    size_t base = (size_t)slab * 20480;
    for (int f = t; f < 5120; f += 256) {
      int e0 = f * 4;
      float v[4];
#pragma unroll
      for (int m = 0; m < 4; ++m) {
        int e = e0 + m, ij = e / 5, d = e - ij * 5;
        v[m] = (d == (int)cur_g[ij]) ? 1.0f : 0.0f;
      }
      stv4(out, (OFF_TOTE + base) / 4 + f, bf, v[0], v[1], v[2], v[3]);
    }
    if (k == 0) {
      size_t src4 = (size_t)b * 5120;
      for (int f = t; f < 5120; f += 256)
        cpy4(out, E, (OFF_OUTE + base) / 4 + f, src4 + f, bf);
    } else {
      for (int f = t; f < 5120; f += 256) {
        int e0 = f * 4;
        float v[4];
#pragma unroll
        for (int m = 0; m < 4; ++m) {
          int e = e0 + m, ij = e / 5, d = e - ij * 5;
          v[m] = (d == (int)pre_g[ij]) ? 1.0f : 0.0f;
        }
        stv4(out, (OFF_OUTE + base) / 4 + f, bf, v[0], v[1], v[2], v[3]);
      }
    }
  } else {
    int b = (int)blockIdx.x - 1600;  // 0..31
    if (t < 64) vf[t] = read_mask(M, b * NN + t) ? 1 : 0;
    for (int x = t; x < 800; x += 256)
      ((uint32_t*)sn)[x] =
          ((const uint32_t*)(ws + WS_S2N + (size_t)b * STEPS * 64))[x];
    __syncthreads();
    size_t base0 = (size_t)b * 25600;
    for (int f = t; f < 6400; f += 256) {
      int e0 = f * 4;
      int k = e0 >> 9, i = (e0 >> 3) & 63;
      int s = (int)sn[k * 64 + i];
      bool va = vf[i] != 0;
      float v[4];
#pragma unroll
      for (int m = 0; m < 4; ++m) {
        int d = (e0 + m) & 7;
        v[m] = (va && d == s) ? 1.0f : 0.0f;
      }
      stv4(out, base0 / 4 + f, bf, v[0], v[1], v[2], v[3]);
    }
    for (int f = t; f < 6400; f += 256) {
      int e0 = f * 4;
      int k = e0 >> 9, i = (e0 >> 3) & 63;
      if (k == 0) {
        cpy4(out, X, (OFF_OUTX + base0) / 4 + f,
             ((size_t)b * 512 + (size_t)(e0 & 511)) / 4, bf);
      } else {
        int s = (int)sn[(k - 1) * 64 + i];
        bool va = vf[i] != 0;
        float v[4];
#pragma unroll
        for (int m = 0; m < 4; ++m) {
          int d = (e0 + m) & 7;
          v[m] = (va && d == s) ? 1.0f : 0.0f;
        }
        stv4(out, (OFF_OUTX + base0) / 4 + f, bf, v[0], v[1], v[2], v[3]);
      }
    }
  }
}

// ---------------- fallback: r8's passing single kernel ----------------
__global__ __launch_bounds__(256) void lang_kernel(
    const void* __restrict__ X, const void* __restrict__ E,
    const void* __restrict__ M, const void* __restrict__ gammas,
    const void* __restrict__ Wx, const void* __restrict__ We,
    void* __restrict__ out) {
  __shared__ uint32_t skeys[STEPS * 2];
  __shared__ float stab[STEPS * DXC * DXC];
  const bool edge_blk = blockIdx.x < 512;
  const int t = threadIdx.x;
  const bool bf = detect_bf16(X);

  if (t < STEPS) {
    uint32_t f0, f1, a0, a1;
    tf2x32(0u, 42u, 0u, (uint32_t)t, f0, f1);
    tf2x32(f0, f1, 0u, edge_blk ? 1u : 0u, a0, a1);
    skeys[2 * t] = a0; skeys[2 * t + 1] = a1;
  }
  if (edge_blk) {
    for (int task = t; task < STEPS * DEC; task += 256) {
      int k = task / DEC, c = task % DEC;
      fill_logp<DEC>(We, bf, ld(gammas, k, bf), c, &stab[(k * DEC + c) * DEC]);
    }
  } else {
    for (int task = t; task < STEPS * DXC; task += 256) {
      int k = task / DXC, c = task % DXC;
      fill_logp<DXC>(Wx, bf, ld(gammas, k, bf), c, &stab[(k * DXC + c) * DXC]);
    }
  }
  __syncthreads();

  if (edge_blk) {
    int tid = blockIdx.x * 256 + threadIdx.x;
    int b = tid >> 12, rem = tid & 4095, i = rem >> 6, j = rem & 63;
    bool valid = (i != j) && read_mask(M, b * NN + i) && read_mask(M, b * NN + j);
    int lo = i < j ? i : j, hi = i < j ? j : i;
    int cur = 0;
    if (valid) {
      size_t crow = (((size_t)(b * NN + lo)) * NN + hi) * DEC;
      float bst = ld(E, crow, bf);
      for (int d = 1; d < DEC; ++d) {
        float v = ld(E, crow + d, bf);
        if (v > bst) { bst = v; cur = d; }
      }
    }
    uint32_t base = (uint32_t)((((b * NN) + lo) * NN + hi) * DEC);
#pragma clang loop unroll(disable)
    for (int k = 0; k < STEPS; ++k) {
      size_t tp = ((((size_t)b * STEPS + k) * NN + i) * NN + j) * DEC;
      if (k == 0) {
        for (int d = 0; d < DEC; ++d)
          st(out, OFF_OUTE + tp + d, bf, ld(E, (size_t)tid * DEC + d, bf));
      } else {
        for (int d = 0; d < DEC; ++d)
          st(out, OFF_OUTE + tp + d, bf, (valid && d == cur) ? 1.0f : 0.0f);
      }
      int nxt = 0;
      if (valid) {
        const float* le = stab + (k * DEC + cur) * DEC;
        uint32_t k0 = skeys[2 * k], k1 = skeys[2 * k + 1];
        float bst = -3.0e38f;
        for (int d = 0; d < DEC; ++d) {
          float s = le[d] + gumbel_part(k0, k1, base + (uint32_t)d);
          if (s > bst) { bst = s; nxt = d; }
        }
      }
      for (int d = 0; d < DEC; ++d)
        st(out, OFF_TOTE + tp + d, bf, (valid && d == nxt) ? 1.0f : 0.0f);
      cur = nxt;
    }
  } else {
    int tid = (int)(blockIdx.x - 512) * 256 + threadIdx.x;
    if (tid >= BSZ * NN) return;
    int b = tid >> 6, i = tid & 63;
    bool valid = read_mask(M, tid);
    int cur = 0;
    {
      float bst = ld(X, (size_t)tid * DXC, bf);
      for (int d = 1; d < DXC; ++d) {
        float v = ld(X, (size_t)tid * DXC + d, bf);
        if (v > bst) { bst = v; cur = d; }
      }
    }
    uint32_t base = (uint32_t)(tid * DXC);
#pragma clang loop unroll(disable)
    for (int k = 0; k < STEPS; ++k) {
      size_t tp = (((size_t)b * STEPS + k) * NN + i) * DXC;
      if (k == 0) {
        for (int d = 0; d < DXC; ++d)
          st(out, OFF_OUTX + tp + d, bf, ld(X, (size_t)tid * DXC + d, bf));
      } else {
        for (int d = 0; d < DXC; ++d)
          st(out, OFF_OUTX + tp + d, bf, (valid && d == cur) ? 1.0f : 0.0f);
      }
      int nxt = 0;
      if (valid) {
        const float* lx = stab + (k * DXC + cur) * DXC;
        uint32_t k0 = skeys[2 * k], k1 = skeys[2 * k + 1];
        float bst = -3.0e38f;
        for (int d = 0; d < DXC; ++d) {
          float s = lx[d] + gumbel_part(k0, k1, base + (uint32_t)d);
          if (s > bst) { bst = s; nxt = d; }
        }
      }
      for (int d = 0; d < DXC; ++d)
        st(out, tp + d, bf, (valid && d == nxt) ? 1.0f : 0.0f);
      cur = nxt;
    }
  }
}

extern "C" void kernel_launch(void* const* d_in, const int* in_sizes, int n_in,
                              void* d_out, int out_size, void* d_ws, size_t ws_size,
                              hipStream_t stream) {
  (void)out_size;
  const void* X = d_in[0];
  const void* E = d_in[1];
  const void* M = d_in[2];
  const void* G = d_in[3];
  const void* Wx = d_in[4];
  const void* We = d_in[5];
  for (int i = 0; i < n_in && i < 6; ++i) {
    switch (in_sizes[i]) {
      case 16384:  X = d_in[i]; break;
      case 655360: E = d_in[i]; break;
      case 2048:   M = d_in[i]; break;
      case 50:     G = d_in[i]; break;
      case 64:     Wx = d_in[i]; break;
      case 25:     We = d_in[i]; break;
      default: break;
    }
  }
  if (ws_size >= WS_NEED) {
    uint8_t* ws = (uint8_t*)d_ws;
    hipLaunchKernelGGL(prep_kernel, dim3(1), dim3(256), 0, stream,
                       X, G, Wx, We, ws);
    hipLaunchKernelGGL(compact_kernel, dim3(252), dim3(256), 0, stream, M, ws);
    hipLaunchKernelGGL(chain_kernel, dim3(EDGE_BLOCKS + 64), dim3(256), 0,
                       stream, X, E, M, ws);
    hipLaunchKernelGGL(write_kernel, dim3(1632), dim3(256), 0, stream,
                       X, E, M, ws, d_out);
  } else {
    hipLaunchKernelGGL(lang_kernel, dim3(520), dim3(256), 0, stream,
                       X, E, M, G, Wx, We, d_out);
  }
}

// Round 13
// 380.651 us; speedup vs baseline: 1.1470x; 1.1470x over previous
//
#include <hip/hip_runtime.h>
#include <stdint.h>

#pragma clang fp contract(off)

#define STEPS 50
#define BSZ 32
#define NN 64
#define DXC 8
#define DEC 5
// Output order (scan-unpack): out0=stacked Xn, out1=stacked En,
// out2=stacked Xc, out3=stacked Ec.
#define OFF_TOTE 819200UL     // out1 base (elements)
#define OFF_OUTX 33587200UL   // out2 base
#define OFF_OUTE 34406400UL   // out3 base

#define NPAIR 2016            // upper-tri pairs per batch
#define EDGE_CHAINS 64512     // 32*2016
#define EDGE_BLOCKS 1344      // 64512 chains / (12 groups * 4 waves)
// ws layout (bytes)
#define WS_KEYS 0UL            // u32[256]: kx[0..99], ke[100..199], cnt[200]
#define WS_STE  1024UL         // f32[1250]  edge log-prob table
#define WS_STN  6144UL         // f32[3200]  node log-prob table
#define WS_CL   18944UL        // u16[64512] compacted chain ids
#define WS_CB   147968UL       // u32[64512] chain counter-base (=crow)
#define WS_S2E  406016UL       // u8[1600][2016] samples, slab-major
#define WS_S2N  3631616UL      // u8[1600][64]
#define WS_NEED 3734016UL

// ---------------- threefry2x32 (JAX-exact, 20 rounds) ----------------
__device__ __forceinline__ uint32_t rotl32(uint32_t x, int d) {
  return (x << d) | (x >> (32 - d));
}

__device__ __forceinline__ void tf2x32(uint32_t k0, uint32_t k1,
                                       uint32_t x0, uint32_t x1,
                                       uint32_t& o0, uint32_t& o1) {
  uint32_t ks2 = k0 ^ k1 ^ 0x1BD11BDAu;
  x0 += k0; x1 += k1;
#define TF_R(r) { x0 += x1; x1 = rotl32(x1, (r)); x1 ^= x0; }
  TF_R(13) TF_R(15) TF_R(26) TF_R(6)
  x0 += k1; x1 += ks2 + 1u;
  TF_R(17) TF_R(29) TF_R(16) TF_R(24)
  x0 += ks2; x1 += k0 + 2u;
  TF_R(13) TF_R(15) TF_R(26) TF_R(6)
  x0 += k0; x1 += k1 + 3u;
  TF_R(17) TF_R(29) TF_R(16) TF_R(24)
  x0 += k1; x1 += ks2 + 4u;
  TF_R(13) TF_R(15) TF_R(26) TF_R(6)
  x0 += ks2; x1 += k0 + 5u;
#undef TF_R
  o0 = x0; o1 = x1;
}

__device__ __forceinline__ float logf_cr(float x) { return (float)log((double)x); }
__device__ __forceinline__ float expf_cr(float x) { return (float)exp((double)x); }

// JAX PARTITIONABLE random_bits: bits[i] = o0 ^ o1 of cipher(key, (hi=0, lo=i)).
__device__ __forceinline__ uint32_t tf_bits(uint32_t k0, uint32_t k1,
                                            uint32_t idx) {
  uint32_t o0, o1;
  tf2x32(k0, k1, 0u, idx, o0, o1);
  return o0 ^ o1;
}
// uniform(tiny,1) == max(uf, tiny) bit-exactly
__device__ __forceinline__ float u_from_bits(uint32_t bits) {
  float uf = __uint_as_float((bits >> 9) | 0x3f800000u) - 1.0f;
  return fmaxf(uf, 1.1754943508222875e-38f);
}
// exact gumbel (CR fp32 logs via f64) — the reference-matching value
__device__ __forceinline__ float gumbel_inl(uint32_t k0, uint32_t k1,
                                            uint32_t idx) {
  float u = u_from_bits(tf_bits(k0, k1, idx));
  return -logf_cr(-logf_cr(u));
}
__device__ __attribute__((noinline)) float gumbel_part(uint32_t k0, uint32_t k1,
                                                       uint32_t idx) {
  return gumbel_inl(k0, k1, idx);
}
// cold exact path from precomputed u (keeps f64 out of the hot loop)
__device__ __attribute__((noinline)) float gumbel_exact_u(float u) {
  return -logf_cr(-logf_cr(u));
}
// fast screen: hw v_log_f32 approx gumbel + conservative error bound.
// |hw log2 err| <= ~2^-21*(|res|+1) assumed (spec ~1 ulp); eps inflates as
// t->0 (u->1) so low-relative-accuracy regimes route to the exact path.
__device__ __forceinline__ void gumbel_approx(float u, float& g, float& eps) {
  float l2u = __builtin_amdgcn_logf(u);                  // v_log_f32 (log2)
  float t = fmaxf(-0.69314718055994531f * l2u, 1e-30f);  // ~ -ln(u) > 0
  float l2t = __builtin_amdgcn_logf(t);
  g = -0.69314718055994531f * l2t;
  eps = 1.0e-6f * ((t + 1.0f) / t + fabsf(g) + 2.0f);
}

// dtype auto-detect on X's first 32 bytes.
__device__ __forceinline__ bool detect_bf16(const void* X) {
  const uint16_t* u = (const uint16_t*)X;
  int c = 0;
  for (int i = 0; i < 16; ++i) c += (u[i] == 0x3F80u);
  return c >= 2;
}

__device__ __forceinline__ float ld(const void* p, size_t i, bool bf) {
  if (bf) return __uint_as_float(((uint32_t)((const uint16_t*)p)[i]) << 16);
  return ((const float*)p)[i];
}
__device__ __forceinline__ void st(void* p, size_t i, bool bf, float v) {
  if (bf) ((uint16_t*)p)[i] = (uint16_t)(__float_as_uint(v) >> 16);
  else ((float*)p)[i] = v;
}
__device__ __forceinline__ void stv4(void* p, size_t e4, bool bf,
                                     float a, float b, float c, float d) {
  if (!bf) {
    float4 v; v.x = a; v.y = b; v.z = c; v.w = d;
    ((float4*)p)[e4] = v;
  } else {
    ushort4 v;
    v.x = (uint16_t)(__float_as_uint(a) >> 16);
    v.y = (uint16_t)(__float_as_uint(b) >> 16);
    v.z = (uint16_t)(__float_as_uint(c) >> 16);
    v.w = (uint16_t)(__float_as_uint(d) >> 16);
    ((ushort4*)p)[e4] = v;
  }
}
__device__ __forceinline__ void cpy4(void* dst, const void* src, size_t de4,
                                     size_t se4, bool bf) {
  if (!bf) ((float4*)dst)[de4] = ((const float4*)src)[se4];
  else ((uint2*)dst)[de4] = ((const uint2*)src)[se4];
}

__device__ __forceinline__ bool read_mask(const void* mp, int idx) {
  const uint8_t* m8 = (const uint8_t*)mp;
  uint8_t b1 = m8[1];
  if (b1 == 0) return ((const uint32_t*)mp)[idx] != 0;
  if (b1 == 0x3F) return ((const uint16_t*)mp)[idx] != 0;
  return m8[idx] != 0;
}

// fp32 pred pipeline for current class c, reference op order, exp/log CR.
template <int D>
__device__ void fill_logp(const void* __restrict__ W, bool bf, float gamma,
                          int c, float* __restrict__ out) {
  float t[D];
  for (int d = 0; d < D; ++d) t[d] = ld(W, c * D + d, bf);
  float m = t[0];
  for (int d = 1; d < D; ++d) m = fmaxf(m, t[d]);
  float u[D];
  for (int d = 0; d < D; ++d) u[d] = expf_cr(t[d] - m);
  float s = 0.0f;
  for (int d = 0; d < D; ++d) s += u[d];
  float p[D];
  for (int d = 0; d < D; ++d) p[d] = (u[d] / s) * gamma;
  p[c] = 0.0f;
  float s1 = 0.0f;
  for (int d = 0; d < D; ++d) s1 += p[d];
  float r = fmaxf(1.0f - s1, 0.0f);
  p[c] = r;
  float s2 = 0.0f;
  for (int d = 0; d < D; ++d) s2 += p[d];
  for (int d = 0; d < D; ++d) out[d] = logf_cr(p[d] / s2);
}

__device__ __forceinline__ void pair_decode(int q, int& lo, int& hi) {
  lo = 0; int rem = q;
  while (rem >= 63 - lo) { rem -= 63 - lo; lo++; }
  hi = lo + 1 + rem;
}

// ---------------- K0: keys + both log-prob tables + zero counter -----------
__global__ __launch_bounds__(256) void prep_kernel(
    const void* __restrict__ X, const void* __restrict__ gammas,
    const void* __restrict__ Wx, const void* __restrict__ We,
    uint8_t* __restrict__ ws) {
  const int t = threadIdx.x;
  const bool bf = detect_bf16(X);
  uint32_t* wk = (uint32_t*)(ws + WS_KEYS);
  if (t == 0) wk[200] = 0u;
  if (t < STEPS) {
    uint32_t f0, f1, a0, a1;
    tf2x32(0u, 42u, 0u, (uint32_t)t, f0, f1);
    tf2x32(f0, f1, 0u, 0u, a0, a1);  // kx
    wk[2 * t] = a0; wk[2 * t + 1] = a1;
    tf2x32(f0, f1, 0u, 1u, a0, a1);  // ke
    wk[100 + 2 * t] = a0; wk[101 + 2 * t] = a1;
  }
  for (int task = t; task < STEPS * DEC; task += 256)
    fill_logp<DEC>(We, bf, ld(gammas, task / DEC, bf), task % DEC,
                   (float*)(ws + WS_STE) + task * DEC);
  for (int task = t; task < STEPS * DXC; task += 256)
    fill_logp<DXC>(Wx, bf, ld(gammas, task / DXC, bf), task % DXC,
                   (float*)(ws + WS_STN) + task * DXC);
}

// ---------------- Kc: compact valid edge chains -> ids + counter bases -----
__global__ __launch_bounds__(256) void compact_kernel(const void* __restrict__ M,
                                                      uint8_t* __restrict__ ws) {
  int chain = blockIdx.x * 256 + threadIdx.x;
  if (chain >= EDGE_CHAINS) return;
  int b = chain / NPAIR, q = chain % NPAIR, lo, hi;
  pair_decode(q, lo, hi);
  if (read_mask(M, b * NN + lo) && read_mask(M, b * NN + hi)) {
    uint32_t slot = atomicAdd((uint32_t*)(ws + WS_KEYS) + 200, 1u);
    ((uint16_t*)(ws + WS_CL))[slot] = (uint16_t)chain;
    ((uint32_t*)(ws + WS_CB))[slot] =
        (uint32_t)(((b * NN + lo) * NN + hi) * DEC);
  }
}

// ---------------- K1: fused chains, hw-log screen + exact fallback ---------
// blocks [0,1344): edge — 5 lanes per compacted chain, 12 groups/wave.
// blocks [1344,1408): node — 8 lanes per node chain, 8 groups/wave.
// Screening is argmax-exact: decided only when the approx winner's lower
// bound strictly clears every rival's upper bound (unique true max).
__global__ __launch_bounds__(256) void chain_kernel(
    const void* __restrict__ X, const void* __restrict__ E,
    const void* __restrict__ M, uint8_t* __restrict__ ws) {
  __shared__ float stab[STEPS * DXC * DXC];
  __shared__ uint32_t skeys[STEPS * 2];
  const bool edge_blk = blockIdx.x < EDGE_BLOCKS;
  const int t = threadIdx.x;
  const bool bf = detect_bf16(X);
  const uint32_t* wk = (const uint32_t*)(ws + WS_KEYS);

  if (edge_blk) {
    for (int x = t; x < STEPS * DEC * DEC; x += 256)
      stab[x] = ((const float*)(ws + WS_STE))[x];
    if (t < STEPS * 2) skeys[t] = wk[100 + t];
  } else {
    for (int x = t; x < STEPS * DXC * DXC; x += 256)
      stab[x] = ((const float*)(ws + WS_STN))[x];
    if (t < STEPS * 2) skeys[t] = wk[t];
  }
  __syncthreads();

  const int lane = t & 63;
  if (edge_blk) {
    if (lane >= 60) return;  // 12 groups of 5 per wave
    const uint32_t cnt = wk[200];
    int grp = lane / 5, d = lane - grp * 5, gb = grp * 5;
    uint32_t slot = (uint32_t)((blockIdx.x * 4 + (t >> 6)) * 12 + grp);
    if (slot >= cnt) return;
    int chain = (int)((const uint16_t*)(ws + WS_CL))[slot];
    uint32_t cb = ((const uint32_t*)(ws + WS_CB))[slot];
    int b = chain / NPAIR, q = chain - b * NPAIR;
    float v = ld(E, (size_t)cb + d, bf);
    int cur = 0;
    {
      float bst = __shfl(v, gb, 64);
      for (int j = 1; j < DEC; ++j) {
        float vj = __shfl(v, gb + j, 64);
        if (vj > bst) { bst = vj; cur = j; }
      }
    }
    uint8_t* s2e = ws + WS_S2E;
#pragma clang loop unroll(disable)
    for (int k = 0; k < STEPS; ++k) {
      uint32_t k0 = skeys[2 * k], k1 = skeys[2 * k + 1];
      float u = u_from_bits(tf_bits(k0, k1, cb + (uint32_t)d));
      float ga, ea;
      gumbel_approx(u, ga, ea);
      float sa = stab[(k * DEC + cur) * DEC + d] + ga;
      float sj[DEC], ej[DEC];
#pragma unroll
      for (int j = 0; j < DEC; ++j) {
        sj[j] = __shfl(sa, gb + j, 64);
        ej[j] = __shfl(ea, gb + j, 64);
      }
      int idx = 0; float vmax = sj[0];
#pragma unroll
      for (int j = 1; j < DEC; ++j)
        if (sj[j] > vmax) { vmax = sj[j]; idx = j; }
      bool decided = true;
      float lo_ = vmax - ej[idx];
#pragma unroll
      for (int j = 0; j < DEC; ++j)
        if (j != idx && sj[j] + ej[j] >= lo_) decided = false;
      int nxt = idx;
      if (!decided) {  // group-uniform branch; bit-exact CR path
        float se = stab[(k * DEC + cur) * DEC + d] + gumbel_exact_u(u);
        float bst = __shfl(se, gb, 64);
        nxt = 0;
        for (int j = 1; j < DEC; ++j) {
          float sje = __shfl(se, gb + j, 64);
          if (sje > bst) { bst = sje; nxt = j; }  // first-max
        }
      }
      if (d == 0) s2e[(size_t)(b * STEPS + k) * NPAIR + q] = (uint8_t)nxt;
      cur = nxt;
    }
  } else {
    int grp = lane >> 3, d = lane & 7, gb = grp * 8;
    int node = ((int)blockIdx.x - EDGE_BLOCKS) * 32 + (t >> 3);
    if (node >= BSZ * NN) return;
    if (!read_mask(M, node)) return;
    int b = node >> 6, i = node & 63;
    float v = ld(X, (size_t)node * DXC + d, bf);
    int cur = 0;
    {
      float bst = __shfl(v, gb, 64);
      for (int j = 1; j < DXC; ++j) {
        float vj = __shfl(v, gb + j, 64);
        if (vj > bst) { bst = vj; cur = j; }
      }
    }
    uint8_t* s2n = ws + WS_S2N;
#pragma clang loop unroll(disable)
    for (int k = 0; k < STEPS; ++k) {
      uint32_t k0 = skeys[2 * k], k1 = skeys[2 * k + 1];
      float u = u_from_bits(tf_bits(k0, k1, (uint32_t)(node * DXC + d)));
      float ga, ea;
      gumbel_approx(u, ga, ea);
      float sa = stab[(k * DXC + cur) * DXC + d] + ga;
      float sj[DXC], ej[DXC];
#pragma unroll
      for (int j = 0; j < DXC; ++j) {
        sj[j] = __shfl(sa, gb + j, 64);
        ej[j] = __shfl(ea, gb + j, 64);
      }
      int idx = 0; float vmax = sj[0];
#pragma unroll
      for (int j = 1; j < DXC; ++j)
        if (sj[j] > vmax) { vmax = sj[j]; idx = j; }
      bool decided = true;
      float lo_ = vmax - ej[idx];
#pragma unroll
      for (int j = 0; j < DXC; ++j)
        if (j != idx && sj[j] + ej[j] >= lo_) decided = false;
      int nxt = idx;
      if (!decided) {
        float se = stab[(k * DXC + cur) * DXC + d] + gumbel_exact_u(u);
        float bst = __shfl(se, gb, 64);
        nxt = 0;
        for (int j = 1; j < DXC; ++j) {
          float sje = __shfl(se, gb + j, 64);
          if (sje > bst) { bst = sje; nxt = j; }
        }
      }
      if (d == 0) s2n[(size_t)(b * STEPS + k) * 64 + i] = (uint8_t)nxt;
      cur = nxt;
    }
  }
}

// ---------------- K3: slab writer, float4 stores ----------------
// blocks [0,1600): edge slab (b,k); [1600,1632): node batch b (all k).
__global__ __launch_bounds__(256) void write_kernel(
    const void* __restrict__ X, const void* __restrict__ E,
    const void* __restrict__ M, const uint8_t* __restrict__ ws,
    void* __restrict__ out) {
  __shared__ uint8_t cur_g[4096];
  __shared__ uint8_t pre_g[4096];
  __shared__ uint8_t sc[NPAIR];
  __shared__ uint8_t sp_[NPAIR];
  __shared__ uint8_t sn[3200];
  __shared__ uint8_t vf[64];
  const bool bf = detect_bf16(X);
  const int t = threadIdx.x;

  if (blockIdx.x < 1600) {
    int slab = blockIdx.x;  // b*50+k
    int b = slab / STEPS, k = slab % STEPS;
    if (t < 64) vf[t] = read_mask(M, b * NN + t) ? 1 : 0;
    const uint8_t* s2e = ws + WS_S2E;
    for (int x = t; x < 504; x += 256) {
      ((uint32_t*)sc)[x] = ((const uint32_t*)(s2e + (size_t)slab * NPAIR))[x];
      if (k > 0)
        ((uint32_t*)sp_)[x] =
            ((const uint32_t*)(s2e + (size_t)(slab - 1) * NPAIR))[x];
    }
    __syncthreads();
    for (int ij = t; ij < 4096; ij += 256) {
      int i = ij >> 6, j = ij & 63;
      uint8_t c = 0xFF, p = 0xFF;
      if (i != j && vf[i] && vf[j]) {
        int lo = i < j ? i : j, hi = i < j ? j : i;
        int q = 63 * lo - ((lo * (lo - 1)) >> 1) + hi - lo - 1;
        c = sc[q];
        if (k > 0) p = sp_[q];
      }
      cur_g[ij] = c; pre_g[ij] = p;
    }
    __syncthreads();
    size_t base = (size_t)slab * 20480;
    for (int f = t; f < 5120; f += 256) {
      int e0 = f * 4;
      float v[4];
#pragma unroll
      for (int m = 0; m < 4; ++m) {
        int e = e0 + m, ij = e / 5, d = e - ij * 5;
        v[m] = (d == (int)cur_g[ij]) ? 1.0f : 0.0f;
      }
      stv4(out, (OFF_TOTE + base) / 4 + f, bf, v[0], v[1], v[2], v[3]);
    }
    if (k == 0) {
      size_t src4 = (size_t)b * 5120;
      for (int f = t; f < 5120; f += 256)
        cpy4(out, E, (OFF_OUTE + base) / 4 + f, src4 + f, bf);
    } else {
      for (int f = t; f < 5120; f += 256) {
        int e0 = f * 4;
        float v[4];
#pragma unroll
        for (int m = 0; m < 4; ++m) {
          int e = e0 + m, ij = e / 5, d = e - ij * 5;
          v[m] = (d == (int)pre_g[ij]) ? 1.0f : 0.0f;
        }
        stv4(out, (OFF_OUTE + base) / 4 + f, bf, v[0], v[1], v[2], v[3]);
      }
    }
  } else {
    int b = (int)blockIdx.x - 1600;  // 0..31
    if (t < 64) vf[t] = read_mask(M, b * NN + t) ? 1 : 0;
    for (int x = t; x < 800; x += 256)
      ((uint32_t*)sn)[x] =
          ((const uint32_t*)(ws + WS_S2N + (size_t)b * STEPS * 64))[x];
    __syncthreads();
    size_t base0 = (size_t)b * 25600;
    for (int f = t; f < 6400; f += 256) {
      int e0 = f * 4;
      int k = e0 >> 9, i = (e0 >> 3) & 63;
      int s = (int)sn[k * 64 + i];
      bool va = vf[i] != 0;
      float v[4];
#pragma unroll
      for (int m = 0; m < 4; ++m) {
        int d = (e0 + m) & 7;
        v[m] = (va && d == s) ? 1.0f : 0.0f;
      }
      stv4(out, base0 / 4 + f, bf, v[0], v[1], v[2], v[3]);
    }
    for (int f = t; f < 6400; f += 256) {
      int e0 = f * 4;
      int k = e0 >> 9, i = (e0 >> 3) & 63;
      if (k == 0) {
        cpy4(out, X, (OFF_OUTX + base0) / 4 + f,
             ((size_t)b * 512 + (size_t)(e0 & 511)) / 4, bf);
      } else {
        int s = (int)sn[(k - 1) * 64 + i];
        bool va = vf[i] != 0;
        float v[4];
#pragma unroll
        for (int m = 0; m < 4; ++m) {
          int d = (e0 + m) & 7;
          v[m] = (va && d == s) ? 1.0f : 0.0f;
        }
        stv4(out, (OFF_OUTX + base0) / 4 + f, bf, v[0], v[1], v[2], v[3]);
      }
    }
  }
}

// ---------------- fallback: r8's passing single kernel ----------------
__global__ __launch_bounds__(256) void lang_kernel(
    const void* __restrict__ X, const void* __restrict__ E,
    const void* __restrict__ M, const void* __restrict__ gammas,
    const void* __restrict__ Wx, const void* __restrict__ We,
    void* __restrict__ out) {
  __shared__ uint32_t skeys[STEPS * 2];
  __shared__ float stab[STEPS * DXC * DXC];
  const bool edge_blk = blockIdx.x < 512;
  const int t = threadIdx.x;
  const bool bf = detect_bf16(X);

  if (t < STEPS) {
    uint32_t f0, f1, a0, a1;
    tf2x32(0u, 42u, 0u, (uint32_t)t, f0, f1);
    tf2x32(f0, f1, 0u, edge_blk ? 1u : 0u, a0, a1);
    skeys[2 * t] = a0; skeys[2 * t + 1] = a1;
  }
  if (edge_blk) {
    for (int task = t; task < STEPS * DEC; task += 256) {
      int k = task / DEC, c = task % DEC;
      fill_logp<DEC>(We, bf, ld(gammas, k, bf), c, &stab[(k * DEC + c) * DEC]);
    }
  } else {
    for (int task = t; task < STEPS * DXC; task += 256) {
      int k = task / DXC, c = task % DXC;
      fill_logp<DXC>(Wx, bf, ld(gammas, k, bf), c, &stab[(k * DXC + c) * DXC]);
    }
  }
  __syncthreads();

  if (edge_blk) {
    int tid = blockIdx.x * 256 + threadIdx.x;
    int b = tid >> 12, rem = tid & 4095, i = rem >> 6, j = rem & 63;
    bool valid = (i != j) && read_mask(M, b * NN + i) && read_mask(M, b * NN + j);
    int lo = i < j ? i : j, hi = i < j ? j : i;
    int cur = 0;
    if (valid) {
      size_t crow = (((size_t)(b * NN + lo)) * NN + hi) * DEC;
      float bst = ld(E, crow, bf);
      for (int d = 1; d < DEC; ++d) {
        float v = ld(E, crow + d, bf);
        if (v > bst) { bst = v; cur = d; }
      }
    }
    uint32_t base = (uint32_t)((((b * NN) + lo) * NN + hi) * DEC);
#pragma clang loop unroll(disable)
    for (int k = 0; k < STEPS; ++k) {
      size_t tp = ((((size_t)b * STEPS + k) * NN + i) * NN + j) * DEC;
      if (k == 0) {
        for (int d = 0; d < DEC; ++d)
          st(out, OFF_OUTE + tp + d, bf, ld(E, (size_t)tid * DEC + d, bf));
      } else {
        for (int d = 0; d < DEC; ++d)
          st(out, OFF_OUTE + tp + d, bf, (valid && d == cur) ? 1.0f : 0.0f);
      }
      int nxt = 0;
      if (valid) {
        const float* le = stab + (k * DEC + cur) * DEC;
        uint32_t k0 = skeys[2 * k], k1 = skeys[2 * k + 1];
        float bst = -3.0e38f;
        for (int d = 0; d < DEC; ++d) {
          float s = le[d] + gumbel_part(k0, k1, base + (uint32_t)d);
          if (s > bst) { bst = s; nxt = d; }
        }
      }
      for (int d = 0; d < DEC; ++d)
        st(out, OFF_TOTE + tp + d, bf, (valid && d == nxt) ? 1.0f : 0.0f);
      cur = nxt;
    }
  } else {
    int tid = (int)(blockIdx.x - 512) * 256 + threadIdx.x;
    if (tid >= BSZ * NN) return;
    int b = tid >> 6, i = tid & 63;
    bool valid = read_mask(M, tid);
    int cur = 0;
    {
      float bst = ld(X, (size_t)tid * DXC, bf);
      for (int d = 1; d < DXC; ++d) {
        float v = ld(X, (size_t)tid * DXC + d, bf);
        if (v > bst) { bst = v; cur = d; }
      }
    }
    uint32_t base = (uint32_t)(tid * DXC);
#pragma clang loop unroll(disable)
    for (int k = 0; k < STEPS; ++k) {
      size_t tp = (((size_t)b * STEPS + k) * NN + i) * DXC;
      if (k == 0) {
        for (int d = 0; d < DXC; ++d)
          st(out, OFF_OUTX + tp + d, bf, ld(X, (size_t)tid * DXC + d, bf));
      } else {
        for (int d = 0; d < DXC; ++d)
          st(out, OFF_OUTX + tp + d, bf, (valid && d == cur) ? 1.0f : 0.0f);
      }
      int nxt = 0;
      if (valid) {
        const float* lx = stab + (k * DXC + cur) * DXC;
        uint32_t k0 = skeys[2 * k], k1 = skeys[2 * k + 1];
        float bst = -3.0e38f;
        for (int d = 0; d < DXC; ++d) {
          float s = lx[d] + gumbel_part(k0, k1, base + (uint32_t)d);
          if (s > bst) { bst = s; nxt = d; }
        }
      }
      for (int d = 0; d < DXC; ++d)
        st(out, tp + d, bf, (valid && d == nxt) ? 1.0f : 0.0f);
      cur = nxt;
    }
  }
}

extern "C" void kernel_launch(void* const* d_in, const int* in_sizes, int n_in,
                              void* d_out, int out_size, void* d_ws, size_t ws_size,
                              hipStream_t stream) {
  (void)out_size;
  const void* X = d_in[0];
  const void* E = d_in[1];
  const void* M = d_in[2];
  const void* G = d_in[3];
  const void* Wx = d_in[4];
  const void* We = d_in[5];
  for (int i = 0; i < n_in && i < 6; ++i) {
    switch (in_sizes[i]) {
      case 16384:  X = d_in[i]; break;
      case 655360: E = d_in[i]; break;
      case 2048:   M = d_in[i]; break;
      case 50:     G = d_in[i]; break;
      case 64:     Wx = d_in[i]; break;
      case 25:     We = d_in[i]; break;
      default: break;
    }
  }
  if (ws_size >= WS_NEED) {
    uint8_t* ws = (uint8_t*)d_ws;
    hipLaunchKernelGGL(prep_kernel, dim3(1), dim3(256), 0, stream,
                       X, G, Wx, We, ws);
    hipLaunchKernelGGL(compact_kernel, dim3(252), dim3(256), 0, stream, M, ws);
    hipLaunchKernelGGL(chain_kernel, dim3(EDGE_BLOCKS + 64), dim3(256), 0,
                       stream, X, E, M, ws);
    hipLaunchKernelGGL(write_kernel, dim3(1632), dim3(256), 0, stream,
                       X, E, M, ws, d_out);
  } else {
    hipLaunchKernelGGL(lang_kernel, dim3(520), dim3(256), 0, stream,
                       X, E, M, G, Wx, We, d_out);
  }
}